// Round 2
// 94.562 us; speedup vs baseline: 1.1264x; 1.1264x over previous
//
#include <hip/hip_runtime.h>

// 20-qubit statevector, 8 layers {Ry x20, CZ chain, Rzz chain}, out = |psi|^2.
// Butterfly restructure: 4 amps/thread in registers; rotations applied on
//  - reg bits (free), lane bits via DPP cross-lane (VALU pipe, no LDS),
//  - wave bits relocated by exactly TWO LDS transpose passes per kernel
//    (double-buffered, XOR-swizzled to the bank floor) -> 2 barriers/kernel
//    instead of 12, ~20 LDS instrs/thread instead of ~90.
// Layouts (tile index n[11:0], thread t[9:0], amp j[1:0]):
//  L0: reg={n1,n0} lanes={n7..n2} wave={n11..n8}   (global-coalesced order)
//  Q : reg={n7,n6} lanes={n5,n4 parked | n11..n8}  wave={n3..n0}
// LOW kernel: A=flat0..10, D, B=flat0..11 ; HI: A=flat12..19, D, B=flat11..19
// phase1@L0: rot n0..n5(A-low) -> pass -> phase2@Q: rot n6..n11 (A-hi, D, B-hi)
// -> pass -> phase3@L0: rot n0..n5 (B-low).
// DPP semantics (verified vs rocPRIM scan idiom): row_shr:N = from lane i-N,
// row_shl:N = from lane i+N. quad_perm/row_ror:8 are direction-proof.

#define QN 20

__device__ __forceinline__ float2 cmulf(float2 a, float2 b) {
    return make_float2(a.x * b.x - a.y * b.y, a.x * b.y + a.y * b.x);
}

// ---- rotation on register bits: w = (cos, sin) -----------------------------
__device__ __forceinline__ void rot2c(float2& x0, float2& x1, float2 w) {
    float2 t0 = make_float2(w.x * x0.x - w.y * x1.x, w.x * x0.y - w.y * x1.y);
    float2 t1 = make_float2(w.y * x0.x + w.x * x1.x, w.y * x0.y + w.x * x1.y);
    x0 = t0; x1 = t1;
}
__device__ __forceinline__ void rot4c(float2& a0, float2& a1, float2& a2, float2& a3,
                                      float2 wa, float2 wb) {
    rot2c(a0, a1, wa); rot2c(a2, a3, wa);
    rot2c(a0, a2, wb); rot2c(a1, a3, wb);
}

// ---- DPP cross-lane partner fetch (xor distance X in {1,2,4,8}) ------------
template<int X>
__device__ __forceinline__ float2 xpart(float2 v, int t) {
    int sx = __float_as_int(v.x), sy = __float_as_int(v.y);
    if constexpr (X == 4) {
        // row_shr:4 (0x114): lane i <- lane i-4 (valid when i%16 >= 4, i.e. t&4=1 group ok)
        // row_shl:4 (0x104): lane i <- lane i+4 (valid for t&4=0 group)
        int ax = __builtin_amdgcn_update_dpp(sx, sx, 0x114, 0xF, 0xF, false);
        int ay = __builtin_amdgcn_update_dpp(sy, sy, 0x114, 0xF, 0xF, false);
        int bx = __builtin_amdgcn_update_dpp(sx, sx, 0x104, 0xF, 0xF, false);
        int by = __builtin_amdgcn_update_dpp(sy, sy, 0x104, 0xF, 0xF, false);
        bool hi = (t & 4) != 0;   // hi lanes need partner i-4 -> row_shr
        return make_float2(__int_as_float(hi ? ax : bx), __int_as_float(hi ? ay : by));
    } else {
        // xor1: quad_perm[1,0,3,2]=0xB1; xor2: quad_perm[2,3,0,1]=0x4E;
        // xor8: row_ror:8=0x128 ((i+8)%16 == i^8 within a 16-row)
        constexpr int ctrl = (X == 1) ? 0xB1 : (X == 2) ? 0x4E : 0x128;
        return make_float2(
            __int_as_float(__builtin_amdgcn_update_dpp(sx, sx, ctrl, 0xF, 0xF, false)),
            __int_as_float(__builtin_amdgcn_update_dpp(sy, sy, ctrl, 0xF, 0xF, false)));
    }
}

// Ry on a lane bit: own' = c*own + (side? +s : -s)*partner
template<int X>
__device__ __forceinline__ void lrot4(float2& a0, float2& a1, float2& a2, float2& a3,
                                      float2 w, int t) {
    float ss = (t & X) ? w.y : -w.y;
    float2 p0 = xpart<X>(a0, t), p1 = xpart<X>(a1, t),
           p2 = xpart<X>(a2, t), p3 = xpart<X>(a3, t);
    a0 = make_float2(fmaf(ss, p0.x, w.x * a0.x), fmaf(ss, p0.y, w.x * a0.y));
    a1 = make_float2(fmaf(ss, p1.x, w.x * a1.x), fmaf(ss, p1.y, w.x * a1.y));
    a2 = make_float2(fmaf(ss, p2.x, w.x * a2.x), fmaf(ss, p2.y, w.x * a2.y));
    a3 = make_float2(fmaf(ss, p3.x, w.x * a3.x), fmaf(ss, p3.y, w.x * a3.y));
}

// ---- diagonal (CZ chain + Rzz chain) phase ---------------------------------
__device__ __forceinline__ float2 dphase(int x, const float2* Plo, const float2* Phh) {
    int y = (x ^ (x >> 1)) & 0x7FFFF;
    float2 p = cmulf(Plo[y & 1023], Phh[y >> 10]);
    int sgn = (__popc(x & (x >> 1) & 0x7FFFF) & 1) << 31;
    p.x = __int_as_float(__float_as_int(p.x) ^ sgn);
    p.y = __int_as_float(__float_as_int(p.y) ^ sgn);
    return p;
}

__device__ __forceinline__ void build_D(float2* Plo, float2* Phh,
                                        const float* __restrict__ ph, int t) {
    float pw[19];
    #pragma unroll
    for (int j = 0; j < 19; ++j) pw[j] = ph[18 - j];   // uniform loads
    float S = 0.f;
    #pragma unroll
    for (int j = 0; j < 19; ++j) S += pw[j];
    float ang = 0.f;
    #pragma unroll
    for (int j = 0; j < 10; ++j) if ((t >> j) & 1) ang += pw[j];
    Plo[t] = make_float2(cosf(ang), sinf(ang));
    if (t < 512) {
        float a2 = -0.5f * S;
        #pragma unroll
        for (int j = 0; j < 9; ++j) if ((t >> j) & 1) a2 += pw[10 + j];
        Phh[t] = make_float2(cosf(a2), sinf(a2));
    }
}

// ---- LDS transpose passes (bank-floor XOR swizzles) ------------------------
// m(n) = n6|n7<<1|n8<<2..n11<<5|n4<<6|n5<<7|n0<<8|n1<<9|n2<<10|n3<<11
// store at p = m ^ (m[11:10]<<2) ^ (m[7:6]<<4)
__device__ __forceinline__ void pass_w1(float2* buf, int t,
                                        float2 a0, float2 a1, float2 a2, float2 a3) {
    int mb = ((t >> 4) & 3) | (((t >> 6) & 0xF) << 2) |
             (((t >> 2) & 3) << 6) | ((t & 3) << 10);
    int pb = mb ^ ((t & 3) << 2) ^ (((t >> 2) & 3) << 4);
    buf[pb] = a0; buf[pb | 256] = a1; buf[pb | 512] = a2; buf[pb | 768] = a3;
}
__device__ __forceinline__ void pass_r1(const float2* buf, int t,
                                        float2& a0, float2& a1, float2& a2, float2& a3) {
    int rb = (4 * t) ^ (((t >> 8) & 3) << 2) ^ (((t >> 4) & 3) << 4);
    const float4* b4 = (const float4*)(buf + rb);
    float4 u = b4[0], w = b4[1];
    a0 = make_float2(u.x, u.y); a1 = make_float2(u.z, u.w);
    a2 = make_float2(w.x, w.y); a3 = make_float2(w.z, w.w);
}
// Q-thread's n base (j in bits 6,7): n = nb | (j<<6)
__device__ __forceinline__ int q_nb(int t) {
    return ((t >> 6) & 0xF) | (((t >> 4) & 3) << 4) | ((t & 0xF) << 8);
}
// store at q = n ^ n[9:8] ^ (n[11:10]<<2) ^ (n[7:6]<<4)
__device__ __forceinline__ void pass_w2(float2* buf, int t,
                                        float2 a0, float2 a1, float2 a2, float2 a3) {
    int nb = q_nb(t);
    int qb = nb ^ (t & 3) ^ (((t >> 2) & 3) << 2);
    buf[qb] = a0; buf[qb ^ 0x50] = a1; buf[qb ^ 0xA0] = a2; buf[qb ^ 0xF0] = a3;
}
__device__ __forceinline__ void pass_r2(const float2* buf, int t,
                                        float2& a0, float2& a1, float2& a2, float2& a3) {
    int rb = (4 * t) ^ (((t >> 8) & 3) << 2) ^ (((t >> 4) & 3) << 4);
    const float4* b4 = (const float4*)(buf + rb);
    float4 u = b4[0], w = b4[1];
    float2 r0 = make_float2(u.x, u.y), r1 = make_float2(u.z, u.w),
           r2 = make_float2(w.x, w.y), r3 = make_float2(w.z, w.w);
    int k = (t >> 6) & 3;                       // wave-uniform in-quad xor
    if (k & 1) { float2 x = r0; r0 = r1; r1 = x; x = r2; r2 = r3; r3 = x; }
    if (k & 2) { float2 x = r0; r0 = r2; r2 = x; x = r1; r1 = r3; r3 = x; }
    a0 = r0; a1 = r1; a2 = r2; a3 = r3;
}

__device__ __forceinline__ int hi_x(int n, int blk) {
    return ((n >> 3) << 11) | (blk << 3) | (n & 7);
}

// ---------------- LOW kernel: tile = contiguous 4096 amps -------------------
template<bool LAST>
__global__ __launch_bounds__(1024)
void low_kernel(float2* __restrict__ psi, const float2* __restrict__ cA,
                const float2* __restrict__ cB, const float* __restrict__ ph,
                float* __restrict__ outP) {
    __shared__ __align__(16) float2 bufA[4096];
    __shared__ __align__(16) float2 bufB[4096];
    __shared__ float2 Plo[1024];
    __shared__ float2 Phh[512];
    const int t = threadIdx.x, blk = blockIdx.x;

    const float4* gp = (const float4*)(psi + (blk << 12));
    float4 v0 = gp[2 * t], v1 = gp[2 * t + 1];

    if (!LAST) build_D(Plo, Phh, ph, t);

    float2 a0 = make_float2(v0.x, v0.y), a1 = make_float2(v0.z, v0.w),
           a2 = make_float2(v1.x, v1.y), a3 = make_float2(v1.z, v1.w);

    // phase1 @L0: A flat 0..5
    rot4c(a0, a1, a2, a3, cA[0], cA[1]);
    lrot4<1>(a0, a1, a2, a3, cA[2], t);
    lrot4<2>(a0, a1, a2, a3, cA[3], t);
    lrot4<4>(a0, a1, a2, a3, cA[4], t);
    lrot4<8>(a0, a1, a2, a3, cA[5], t);

    pass_w1(bufA, t, a0, a1, a2, a3);
    __syncthreads();                     // bar1 (also covers Plo/Phh writes)
    pass_r1(bufA, t, a0, a1, a2, a3);

    // phase2 @Q: A flat 6..10
    rot4c(a0, a1, a2, a3, cA[6], cA[7]);
    lrot4<1>(a0, a1, a2, a3, cA[8], t);
    lrot4<2>(a0, a1, a2, a3, cA[9], t);
    lrot4<4>(a0, a1, a2, a3, cA[10], t);

    int nb = q_nb(t);
    if (LAST) {
        // |amp|^2 -> float buffer -> coalesced float4 out (D_7 elided)
        float* bf = (float*)bufB;
        int qb = nb ^ (t & 3) ^ (((t >> 2) & 3) << 2);
        bf[qb]        = a0.x * a0.x + a0.y * a0.y;
        bf[qb ^ 0x50] = a1.x * a1.x + a1.y * a1.y;
        bf[qb ^ 0xA0] = a2.x * a2.x + a2.y * a2.y;
        bf[qb ^ 0xF0] = a3.x * a3.x + a3.y * a3.y;
        __syncthreads();
        int rb = (4 * t) ^ (((t >> 8) & 3) << 2) ^ (((t >> 4) & 3) << 4);
        float4 u = *(const float4*)(bf + rb);
        int k = (t >> 6) & 3;
        if (k & 1) { float x = u.x; u.x = u.y; u.y = x; x = u.z; u.z = u.w; u.w = x; }
        if (k & 2) { float x = u.x; u.x = u.z; u.z = x; x = u.y; u.y = u.w; u.w = x; }
        *(float4*)(outP + (blk << 12) + 4 * t) = u;
    } else {
        int xb = blk << 12;
        a0 = cmulf(a0, dphase(xb | nb,        Plo, Phh));
        a1 = cmulf(a1, dphase(xb | nb | 0x40, Plo, Phh));
        a2 = cmulf(a2, dphase(xb | nb | 0x80, Plo, Phh));
        a3 = cmulf(a3, dphase(xb | nb | 0xC0, Plo, Phh));
        // B flat 6..11 (still in Q)
        rot4c(a0, a1, a2, a3, cB[6], cB[7]);
        lrot4<1>(a0, a1, a2, a3, cB[8], t);
        lrot4<2>(a0, a1, a2, a3, cB[9], t);
        lrot4<4>(a0, a1, a2, a3, cB[10], t);
        lrot4<8>(a0, a1, a2, a3, cB[11], t);

        pass_w2(bufB, t, a0, a1, a2, a3);
        __syncthreads();                 // bar2
        pass_r2(bufB, t, a0, a1, a2, a3);

        // phase3 @L0: B flat 0..5
        lrot4<1>(a0, a1, a2, a3, cB[2], t);
        lrot4<2>(a0, a1, a2, a3, cB[3], t);
        lrot4<4>(a0, a1, a2, a3, cB[4], t);
        lrot4<8>(a0, a1, a2, a3, cB[5], t);
        rot4c(a0, a1, a2, a3, cB[0], cB[1]);
        float4* op = (float4*)(psi + (blk << 12));
        op[2 * t]     = make_float4(a0.x, a0.y, a1.x, a1.y);
        op[2 * t + 1] = make_float4(a2.x, a2.y, a3.x, a3.y);
    }
}

// ---------------- HI kernel: n3..n11 = flat 11..19, n0..n2 = flat 0..2 ------
__global__ __launch_bounds__(1024)
void hi_kernel(float2* __restrict__ psi, const float2* __restrict__ cA,
               const float2* __restrict__ cB, const float* __restrict__ ph) {
    __shared__ __align__(16) float2 bufA[4096];
    __shared__ __align__(16) float2 bufB[4096];
    __shared__ float2 Plo[1024];
    __shared__ float2 Phh[512];
    const int t = threadIdx.x, blk = blockIdx.x;
    const int ga = ((t >> 1) << 11) | (blk << 3) | ((t & 1) << 2);  // n = 4t+j

    const float4* gp = (const float4*)(psi + ga);
    float4 v0 = gp[0], v1 = gp[1];

    build_D(Plo, Phh, ph, t);

    float2 a0 = make_float2(v0.x, v0.y), a1 = make_float2(v0.z, v0.w),
           a2 = make_float2(v1.x, v1.y), a3 = make_float2(v1.z, v1.w);

    // phase1 @H0: A flat 12,13 (n4,n5)
    lrot4<4>(a0, a1, a2, a3, cA[12], t);
    lrot4<8>(a0, a1, a2, a3, cA[13], t);

    pass_w1(bufA, t, a0, a1, a2, a3);
    __syncthreads();                     // bar1
    pass_r1(bufA, t, a0, a1, a2, a3);

    // phase2 @Q: A flat 14..19 (n6..n11)
    rot4c(a0, a1, a2, a3, cA[14], cA[15]);
    lrot4<1>(a0, a1, a2, a3, cA[16], t);
    lrot4<2>(a0, a1, a2, a3, cA[17], t);
    lrot4<4>(a0, a1, a2, a3, cA[18], t);
    lrot4<8>(a0, a1, a2, a3, cA[19], t);

    int nb = q_nb(t);
    a0 = cmulf(a0, dphase(hi_x(nb,        blk), Plo, Phh));
    a1 = cmulf(a1, dphase(hi_x(nb | 0x40, blk), Plo, Phh));
    a2 = cmulf(a2, dphase(hi_x(nb | 0x80, blk), Plo, Phh));
    a3 = cmulf(a3, dphase(hi_x(nb | 0xC0, blk), Plo, Phh));

    // B flat 14..19 (still in Q)
    rot4c(a0, a1, a2, a3, cB[14], cB[15]);
    lrot4<1>(a0, a1, a2, a3, cB[16], t);
    lrot4<2>(a0, a1, a2, a3, cB[17], t);
    lrot4<4>(a0, a1, a2, a3, cB[18], t);
    lrot4<8>(a0, a1, a2, a3, cB[19], t);

    pass_w2(bufB, t, a0, a1, a2, a3);
    __syncthreads();                     // bar2
    pass_r2(bufB, t, a0, a1, a2, a3);

    // phase3 @H0: B flat 11,12,13 (n3,n4,n5)
    lrot4<2>(a0, a1, a2, a3, cB[11], t);
    lrot4<4>(a0, a1, a2, a3, cB[12], t);
    lrot4<8>(a0, a1, a2, a3, cB[13], t);

    float4* gp2 = (float4*)(psi + ga);
    gp2[0] = make_float4(a0.x, a0.y, a1.x, a1.y);
    gp2[1] = make_float4(a2.x, a2.y, a3.x, a3.y);
}

// ---------------- INIT kernel: synth Ry_0|0>, D_0, B = Ry_1 flat 11..19 -----
// Also dumps cos/sin(theta/2) for all 8 layers to cw for later kernels.
__global__ __launch_bounds__(1024)
void init_kernel(float2* __restrict__ psi, const float* __restrict__ th,
                 const float* __restrict__ ph, float2* __restrict__ cw) {
    __shared__ __align__(16) float2 bufB[4096];
    __shared__ float2 Plo[1024];
    __shared__ float2 Phh[512];
    __shared__ float Alo[1024], Ahi[1024];
    __shared__ float2 cAi[20], cBi[20];
    const int t = threadIdx.x, blk = blockIdx.x;
    const int ga = ((t >> 1) << 11) | (blk << 3) | ((t & 1) << 2);

    if (t < 256) {
        int l = t >> 5, f = t & 31;
        if (f < 20) {
            double a = 0.5 * (double)th[l * 20 + 19 - f];
            float2 w = make_float2((float)cos(a), (float)sin(a));
            cw[l * 20 + f] = w;
            if (l == 0) cAi[f] = w;
            else if (l == 1) cBi[f] = w;
        }
    }
    __syncthreads();                     // bar0: cAi/cBi ready

    build_D(Plo, Phh, ph, t);
    {
        float pl = 1.f, ph2 = 1.f;
        #pragma unroll
        for (int j = 0; j < 10; ++j) {
            pl  *= ((t >> j) & 1) ? cAi[j].y      : cAi[j].x;
            ph2 *= ((t >> j) & 1) ? cAi[10 + j].y : cAi[10 + j].x;
        }
        Alo[t] = pl; Ahi[t] = ph2;
    }
    __syncthreads();                     // bar1: tables ready

    // synth product state directly in Q layout, D_0 fused
    int nb = q_nb(t);
    float2 a0, a1, a2, a3;
    {
        int x0 = hi_x(nb, blk),        x1 = hi_x(nb | 0x40, blk),
            x2 = hi_x(nb | 0x80, blk), x3 = hi_x(nb | 0xC0, blk);
        float m0 = Alo[x0 & 1023] * Ahi[x0 >> 10];
        float m1 = Alo[x1 & 1023] * Ahi[x1 >> 10];
        float m2 = Alo[x2 & 1023] * Ahi[x2 >> 10];
        float m3 = Alo[x3 & 1023] * Ahi[x3 >> 10];
        float2 d0 = dphase(x0, Plo, Phh), d1 = dphase(x1, Plo, Phh),
               d2 = dphase(x2, Plo, Phh), d3 = dphase(x3, Plo, Phh);
        a0 = make_float2(m0 * d0.x, m0 * d0.y);
        a1 = make_float2(m1 * d1.x, m1 * d1.y);
        a2 = make_float2(m2 * d2.x, m2 * d2.y);
        a3 = make_float2(m3 * d3.x, m3 * d3.y);
    }

    // B = Ry_1 flat 14..19 in Q
    rot4c(a0, a1, a2, a3, cBi[14], cBi[15]);
    lrot4<1>(a0, a1, a2, a3, cBi[16], t);
    lrot4<2>(a0, a1, a2, a3, cBi[17], t);
    lrot4<4>(a0, a1, a2, a3, cBi[18], t);
    lrot4<8>(a0, a1, a2, a3, cBi[19], t);

    pass_w2(bufB, t, a0, a1, a2, a3);
    __syncthreads();                     // bar2
    pass_r2(bufB, t, a0, a1, a2, a3);

    // phase3 @H0: B flat 11,12,13
    lrot4<2>(a0, a1, a2, a3, cBi[11], t);
    lrot4<4>(a0, a1, a2, a3, cBi[12], t);
    lrot4<8>(a0, a1, a2, a3, cBi[13], t);

    float4* gp2 = (float4*)(psi + ga);
    gp2[0] = make_float4(a0.x, a0.y, a1.x, a1.y);
    gp2[1] = make_float4(a2.x, a2.y, a3.x, a3.y);
}

extern "C" void kernel_launch(void* const* d_in, const int* in_sizes, int n_in,
                              void* d_out, int out_size, void* d_ws, size_t ws_size,
                              hipStream_t stream) {
    (void)in_sizes; (void)n_in; (void)out_size; (void)ws_size;
    const float* th = (const float*)d_in[0];   // (8,20)
    const float* ph = (const float*)d_in[1];   // (8,19)
    float2* psi = (float2*)d_ws;               // 2^20 complex64 = 8 MB
    float2* cw  = (float2*)((char*)d_ws + (8u << 20));  // 8*20 float2 coeffs
    float* out = (float*)d_out;

    init_kernel      <<<256, 1024, 0, stream>>>(psi, th, ph + 0, cw);
    low_kernel<false><<<256, 1024, 0, stream>>>(psi, cw + 1 * 20, cw + 2 * 20, ph +  19, nullptr);
    hi_kernel        <<<256, 1024, 0, stream>>>(psi, cw + 2 * 20, cw + 3 * 20, ph +  38);
    low_kernel<false><<<256, 1024, 0, stream>>>(psi, cw + 3 * 20, cw + 4 * 20, ph +  57, nullptr);
    hi_kernel        <<<256, 1024, 0, stream>>>(psi, cw + 4 * 20, cw + 5 * 20, ph +  76);
    low_kernel<false><<<256, 1024, 0, stream>>>(psi, cw + 5 * 20, cw + 6 * 20, ph +  95, nullptr);
    hi_kernel        <<<256, 1024, 0, stream>>>(psi, cw + 6 * 20, cw + 7 * 20, ph + 114);
    low_kernel<true ><<<256, 1024, 0, stream>>>(psi, cw + 7 * 20, cw + 7 * 20, ph + 133, out);
}